// Round 14
// baseline (172.700 us; speedup 1.0000x reference)
//
#include <hip/hip_runtime.h>
#include <hip/hip_bf16.h>
#include <math.h>

#define N_NODES 50000
#define N_EDGES 500000
#define H_DIM   128
#define BN_EPS  1e-5f
#define GEMM_GRID ((N_NODES + 31) / 32)     // 1563: 32 nodes per block
#define SCAN_NBLK ((N_NODES + 255) / 256)   // 196
#define RED_NBLK  64                        // stage-1 partial-reduction blocks

typedef __attribute__((ext_vector_type(8))) short short8;
typedef __attribute__((ext_vector_type(4))) float floatx4;

__device__ __forceinline__ ushort f2bf(float x)   // fp32 -> bf16 RNE
{
    unsigned u = __float_as_uint(x);
    unsigned r = (u + 0x7FFFu + ((u >> 16) & 1u)) >> 16;
    return (ushort)r;
}

// ---------------------------------------------------------------------------
// K1: histogram of dst -> deg[]  (+ fused W fp32[k][c] -> bf16 wt[c][k])
// ---------------------------------------------------------------------------
__global__ __launch_bounds__(256) void hist_cvt_kernel(
    const int* __restrict__ dst, int* __restrict__ deg,
    const float* __restrict__ W, ushort* __restrict__ wt)
{
    int e = blockIdx.x * blockDim.x + threadIdx.x;
    if (e < N_EDGES) atomicAdd(&deg[dst[e]], 1);
    if (e < H_DIM * H_DIM) {
        int k = e >> 7, c = e & 127;
        wt[c * 128 + k] = f2bf(W[e]);
    }
}

// ---------------------------------------------------------------------------
// K2 (merged scan): each of 196 blocks redundantly computes ALL 196 chunk
// sums (wave-parallel int4 loads over the L2-hot 200KB deg + shfl reduce),
// Hillis-Steele scans them in LDS for its own offset, then does the in-block
// exclusive scan of its chunk -> rowptr, cursor. One dispatch instead of two.
// ---------------------------------------------------------------------------
__global__ __launch_bounds__(256) void scan_kernel(
    const int* __restrict__ deg,
    int* __restrict__ rowptr, int* __restrict__ cursor)
{
    __shared__ int bs[256];
    __shared__ int s[256];
    int t  = threadIdx.x;
    int wv = t >> 6;          // wave 0..3
    int ln = t & 63;

    // chunk sums: wave wv handles chunks wv, wv+4, ... (64 lanes x int4 each)
    for (int j = wv; j < SCAN_NBLK; j += 4) {
        int base = j * 256 + ln * 4;
        int ssum = 0;
        if (base + 3 < N_NODES) {
            int4 v = *(const int4*)(deg + base);
            ssum = v.x + v.y + v.z + v.w;
        } else {
            #pragma unroll
            for (int k = 0; k < 4; ++k)
                if (base + k < N_NODES) ssum += deg[base + k];
        }
        #pragma unroll
        for (int off = 32; off; off >>= 1)
            ssum += __shfl_xor(ssum, off);
        if (ln == 0) bs[j] = ssum;
    }
    __syncthreads();

    // scan the 196 chunk sums
    int val = (t < SCAN_NBLK) ? bs[t] : 0;
    s[t] = val;
    __syncthreads();
    for (int off = 1; off < 256; off <<= 1) {
        int u = (t >= off) ? s[t - off] : 0;
        __syncthreads();
        s[t] += u;
        __syncthreads();
    }
    int blockoff = (blockIdx.x == 0) ? 0 : s[blockIdx.x - 1];

    // in-block exclusive scan of own chunk
    int i = blockIdx.x * 256 + t;
    int v = (i < N_NODES) ? deg[i] : 0;
    bs[t] = v;
    __syncthreads();
    for (int off = 1; off < 256; off <<= 1) {
        int u = (t >= off) ? bs[t - off] : 0;
        __syncthreads();
        bs[t] += u;
        __syncthreads();
    }
    int excl = bs[t] - v + blockoff;
    if (i < N_NODES) {
        rowptr[i] = excl;
        cursor[i] = excl;
        if (i == N_NODES - 1) rowptr[N_NODES] = excl + v;
    }
}

// ---------------------------------------------------------------------------
// K3: scatter src ids into CSR slots (counting sort by dst)
// ---------------------------------------------------------------------------
__global__ __launch_bounds__(256) void csr_scatter_kernel(
    const int* __restrict__ src, const int* __restrict__ dst,
    int* __restrict__ cursor, int* __restrict__ csr_src)
{
    int e = blockIdx.x * blockDim.x + threadIdx.x;
    if (e >= N_EDGES) return;
    int pos = atomicAdd(&cursor[dst[e]], 1);
    csr_src[pos] = src[e];
}

// ---------------------------------------------------------------------------
// K4 (FUSED v3): per-node online-softmax aggregate -> bf16 LDS A-tile -> MFMA
// GEMM (h = agg @ W, B from L2-hot wt) -> column sum/sq partials.
// v3: plain __launch_bounds__(256) — v2's (256,8) forced VGPR=32 which
// serialized the 4-deep gather pipeline (VALUBusy 37->29%). Allocator should
// land ~40-48 VGPR like the standalone 43us gather; <=64 keeps 8 waves/SIMD.
// ---------------------------------------------------------------------------
__global__ __launch_bounds__(256) void fused_agg_gemm_kernel(
    const float* __restrict__ emb,
    const int* __restrict__ rowptr,
    const int* __restrict__ csr_src,
    const ushort* __restrict__ wt,
    float* __restrict__ h,
    float* __restrict__ partial)
{
    __shared__ ushort A_s[32 * 128];    // 8 KB  bf16 A-tile, swizzled
    __shared__ float  red_s[128 * 9];   // 4.5 KB col-sum contributors
    __shared__ float  red_q[128 * 9];   // 4.5 KB col-sq contributors

    int t  = threadIdx.x;
    int r0 = blockIdx.x * 32;

    // ---- gather + online softmax, 4 nodes per 32-lane group ----
    int grp  = t >> 5;
    int lane = t & 31;

    for (int ri = 0; ri < 4; ++ri) {
        int row  = ri * 8 + grp;            // tile-local row 0..31
        int node = r0 + row;
        float4 o = {0.f, 0.f, 0.f, 0.f};

        if (node < N_NODES) {
            int beg = rowptr[node];
            int end = rowptr[node + 1];
            const float4 b = *((const float4*)(emb + (size_t)node * H_DIM) + lane);

            float m = -INFINITY;
            float denom = 0.f;
            float4 acc = {0.f, 0.f, 0.f, 0.f};

            int e = beg;
            for (; e + 4 <= end; e += 4) {
                float4 a[4];
                float  p[4];
                #pragma unroll
                for (int u = 0; u < 4; ++u) {
                    int s = csr_src[e + u];
                    a[u] = *((const float4*)(emb + (size_t)s * H_DIM) + lane);
                }
                #pragma unroll
                for (int u = 0; u < 4; ++u)
                    p[u] = a[u].x * b.x + a[u].y * b.y + a[u].z * b.z + a[u].w * b.w;
                #pragma unroll
                for (int off = 16; off; off >>= 1) {
                    #pragma unroll
                    for (int u = 0; u < 4; ++u)
                        p[u] += __shfl_xor(p[u], off);
                }
                float mn = fmaxf(fmaxf(fmaxf(p[0], p[1]), fmaxf(p[2], p[3])), m);
                float corr = __expf(m - mn);      // first iter: exp(-inf)=0
                float w[4];
                #pragma unroll
                for (int u = 0; u < 4; ++u) w[u] = __expf(p[u] - mn);
                denom = denom * corr + w[0] + w[1] + w[2] + w[3];
                acc.x = acc.x * corr + a[0].x*w[0] + a[1].x*w[1] + a[2].x*w[2] + a[3].x*w[3];
                acc.y = acc.y * corr + a[0].y*w[0] + a[1].y*w[1] + a[2].y*w[2] + a[3].y*w[3];
                acc.z = acc.z * corr + a[0].z*w[0] + a[1].z*w[1] + a[2].z*w[2] + a[3].z*w[3];
                acc.w = acc.w * corr + a[0].w*w[0] + a[1].w*w[1] + a[2].w*w[2] + a[3].w*w[3];
                m = mn;
            }
            for (; e < end; ++e) {
                int s = csr_src[e];
                float4 a = *((const float4*)(emb + (size_t)s * H_DIM) + lane);
                float p = a.x * b.x + a.y * b.y + a.z * b.z + a.w * b.w;
                #pragma unroll
                for (int off = 16; off; off >>= 1)
                    p += __shfl_xor(p, off);
                float mn   = fmaxf(m, p);
                float corr = __expf(m - mn);
                float w    = __expf(p - mn);
                denom = denom * corr + w;
                acc.x = acc.x * corr + a.x * w;
                acc.y = acc.y * corr + a.y * w;
                acc.z = acc.z * corr + a.z * w;
                acc.w = acc.w * corr + a.w * w;
                m = mn;
            }

            float inv = (end > beg) ? (1.0f / denom) : 0.f;
            o.x = acc.x * inv; o.y = acc.y * inv;
            o.z = acc.z * inv; o.w = acc.w * inv;
        }

        // bf16 -> swizzled LDS A-tile (granule-XOR; lane*4 keeps bit2 intact)
        unsigned lo = (unsigned)f2bf(o.x) | ((unsigned)f2bf(o.y) << 16);
        unsigned hi = (unsigned)f2bf(o.z) | ((unsigned)f2bf(o.w) << 16);
        int col = (lane * 4) ^ ((row & 7) << 3);
        uint2 pk; pk.x = lo; pk.y = hi;
        *(uint2*)&A_s[row * 128 + col] = pk;
    }
    __syncthreads();

    // ---- MFMA GEMM: wave w -> rows (w>>1)*16, cols (w&1)*64.
    //      B fragments straight from global wt (L2-hot, 32 KB). ----
    int w      = t >> 6;
    int lane64 = t & 63;
    int rbase  = (w >> 1) * 16;
    int c0     = (w & 1) * 64;
    int l15    = lane64 & 15;
    int kgrp   = lane64 >> 4;           // 0..3
    int arow   = rbase + l15;
    int k0l    = kgrp * 8;

    floatx4 acc4[4] = {{0.f,0.f,0.f,0.f},{0.f,0.f,0.f,0.f},
                       {0.f,0.f,0.f,0.f},{0.f,0.f,0.f,0.f}};

    #pragma unroll
    for (int ks = 0; ks < 4; ++ks) {
        int k0 = ks * 32 + k0l;
        short8 af = *(const short8*)&A_s[arow * 128 + (k0 ^ ((arow & 7) << 3))];
        #pragma unroll
        for (int ct = 0; ct < 4; ++ct) {
            int col = c0 + ct * 16 + l15;
            short8 bf = *(const short8*)(wt + (size_t)col * 128 + k0);
            acc4[ct] = __builtin_amdgcn_mfma_f32_16x16x32_bf16(af, bf, acc4[ct], 0, 0, 0);
        }
    }

    // epilogue: write h + per-thread column partials (padded rows have acc=0)
    int contrib = (w >> 1) * 4 + kgrp;   // 0..7 per column
    #pragma unroll
    for (int ct = 0; ct < 4; ++ct) {
        int col = c0 + ct * 16 + l15;
        float ps = 0.f, pq = 0.f;
        #pragma unroll
        for (int reg = 0; reg < 4; ++reg) {
            float v = acc4[ct][reg];
            int gr = r0 + rbase + kgrp * 4 + reg;
            if (gr < N_NODES) h[(size_t)gr * H_DIM + col] = v;
            ps += v;
            pq += v * v;
        }
        red_s[col * 9 + contrib] = ps;
        red_q[col * 9 + contrib] = pq;
    }
    __syncthreads();

    float s = 0.f;
    if (t < 128) {
        #pragma unroll
        for (int q = 0; q < 8; ++q) s += red_s[t * 9 + q];
    } else if (t < 256) {
        #pragma unroll
        for (int q = 0; q < 8; ++q) s += red_q[(t - 128) * 9 + q];
    }
    partial[(size_t)blockIdx.x * 256 + t] = s;
}

// ---------------------------------------------------------------------------
// K5: stage-1 partial reduction: 64 blocks sum 1563 rows -> partial2[64][256]
// ---------------------------------------------------------------------------
__global__ __launch_bounds__(256) void reduce_partials_kernel(
    const float* __restrict__ partial, float* __restrict__ partial2)
{
    int t = threadIdx.x;
    int g = blockIdx.x;
    float s = 0.f;
    for (int b = g; b < GEMM_GRID; b += RED_NBLK)
        s += partial[(size_t)b * 256 + t];
    partial2[(size_t)g * 256 + t] = s;
}

// ---------------------------------------------------------------------------
// K6 (merged): each of 512 blocks redundantly folds the 64KB L2-hot partial2
// into scale/shift in LDS (~1us aggregate), then grid-strides the
// normalize+tanh over h in place. Replaces bn_stats + bn_tanh.
// Layout: tot[c] = colsum, tot[128+c] = colsumsq.
// ---------------------------------------------------------------------------
__global__ __launch_bounds__(256) void bn_fold_tanh_kernel(
    const float* __restrict__ partial2,
    const float* __restrict__ gamma,
    const float* __restrict__ beta,
    float* __restrict__ h)
{
    __shared__ float tot[256];
    __shared__ float sc_s[128];
    __shared__ float sh_s[128];
    int t = threadIdx.x;

    float s = 0.f;
    #pragma unroll 8
    for (int b = 0; b < RED_NBLK; ++b)
        s += partial2[b * 256 + t];        // coalesced, L2-hot
    tot[t] = s;
    __syncthreads();
    if (t < 128) {
        float cs = tot[t];
        float cq = tot[t + 128];
        const float invN = 1.0f / (float)N_NODES;
        float mu  = cs * invN;
        float var = cq * invN - mu * mu;   // biased, matches jnp.var
        float sc  = gamma[t] * rsqrtf(var + BN_EPS);
        sc_s[t] = sc;
        sh_s[t] = beta[t] - mu * sc;
    }
    __syncthreads();

    const size_t total4 = (size_t)N_NODES * H_DIM / 4;
    for (size_t i = (size_t)blockIdx.x * 256 + t; i < total4;
         i += (size_t)gridDim.x * 256) {
        size_t idx4 = i * 4;
        int c = (int)(idx4 & (H_DIM - 1));
        float4 v = *(float4*)(h + idx4);
        v.x = tanhf(v.x * sc_s[c + 0] + sh_s[c + 0]);
        v.y = tanhf(v.y * sc_s[c + 1] + sh_s[c + 1]);
        v.z = tanhf(v.z * sc_s[c + 2] + sh_s[c + 2]);
        v.w = tanhf(v.w * sc_s[c + 3] + sh_s[c + 3]);
        *(float4*)(h + idx4) = v;
    }
}

// ---------------------------------------------------------------------------
extern "C" void kernel_launch(void* const* d_in, const int* in_sizes, int n_in,
                              void* d_out, int out_size, void* d_ws, size_t ws_size,
                              hipStream_t stream)
{
    const float* ent_emb = (const float*)d_in[0];
    const float* neigh_w = (const float*)d_in[1];
    const float* gamma   = (const float*)d_in[2];
    const float* beta    = (const float*)d_in[3];
    const int*   src     = (const int*)d_in[4];
    const int*   dst     = (const int*)d_in[5];
    float* out = (float*)d_out;

    int*    deg      = (int*)d_ws;                                   // 50000
    int*    rowptr   = deg + N_NODES;                                // 50001
    int*    cursor   = rowptr + N_NODES + 1;                         // 50000
    int*    csr_src  = cursor + N_NODES;                             // 500000
    float*  partial  = (float*)(csr_src + N_EDGES);                  // 1563*256
    float*  partial2 = partial + (size_t)GEMM_GRID * 256;            // 64*256
    ushort* wt       = (ushort*)(partial2 + (size_t)RED_NBLK * 256); // 16384

    hipMemsetAsync(deg, 0, N_NODES * sizeof(int), stream);

    // CSR build (counting sort by dst) + W->bf16^T fused into hist
    hist_cvt_kernel<<<(N_EDGES + 255) / 256, 256, 0, stream>>>(dst, deg, neigh_w, wt);
    scan_kernel<<<SCAN_NBLK, 256, 0, stream>>>(deg, rowptr, cursor);
    csr_scatter_kernel<<<(N_EDGES + 255) / 256, 256, 0, stream>>>(src, dst, cursor, csr_src);

    // fused: aggregate -> LDS bf16 tile -> MFMA GEMM (B from L2) -> h + stats
    fused_agg_gemm_kernel<<<GEMM_GRID, 256, 0, stream>>>(
        ent_emb, rowptr, csr_src, wt, out, partial);

    // hierarchical BN stats fold + normalize + tanh
    reduce_partials_kernel<<<RED_NBLK, 256, 0, stream>>>(partial, partial2);
    bn_fold_tanh_kernel<<<512, 256, 0, stream>>>(partial2, gamma, beta, out);
}

// Round 15
// 150.597 us; speedup vs baseline: 1.1468x; 1.1468x over previous
//
#include <hip/hip_runtime.h>
#include <hip/hip_bf16.h>
#include <math.h>

#define N_NODES 50000
#define N_EDGES 500000
#define H_DIM   128
#define BN_EPS  1e-5f
#define GEMM_GRID ((N_NODES + 31) / 32)     // 1563: 32 rows per block
#define SCAN_NBLK ((N_NODES + 255) / 256)   // 196
#define RED_NBLK  64                        // stage-1 partial-reduction blocks

typedef __attribute__((ext_vector_type(8))) short short8;
typedef __attribute__((ext_vector_type(4))) float floatx4;

__device__ __forceinline__ ushort f2bf(float x)   // fp32 -> bf16 RNE
{
    unsigned u = __float_as_uint(x);
    unsigned r = (u + 0x7FFFu + ((u >> 16) & 1u)) >> 16;
    return (ushort)r;
}

// ---------------------------------------------------------------------------
// K1: histogram of dst -> deg[]  (+ fused W fp32[k][c] -> bf16 wt[c][k])
// ---------------------------------------------------------------------------
__global__ __launch_bounds__(256) void hist_cvt_kernel(
    const int* __restrict__ dst, int* __restrict__ deg,
    const float* __restrict__ W, ushort* __restrict__ wt)
{
    int e = blockIdx.x * blockDim.x + threadIdx.x;
    if (e < N_EDGES) atomicAdd(&deg[dst[e]], 1);
    if (e < H_DIM * H_DIM) {
        int k = e >> 7, c = e & 127;
        wt[c * 128 + k] = f2bf(W[e]);
    }
}

// ---------------------------------------------------------------------------
// K2a: per-block sums of deg (196 blocks x 256)
// ---------------------------------------------------------------------------
__global__ __launch_bounds__(256) void scan_partial_kernel(
    const int* __restrict__ deg, int* __restrict__ blocksum)
{
    __shared__ int red[256];
    int t = threadIdx.x;
    int i = blockIdx.x * 256 + t;
    red[t] = (i < N_NODES) ? deg[i] : 0;
    __syncthreads();
    #pragma unroll
    for (int off = 128; off; off >>= 1) {
        if (t < off) red[t] += red[t + off];
        __syncthreads();
    }
    if (t == 0) blocksum[blockIdx.x] = red[0];
}

// ---------------------------------------------------------------------------
// K2b: every block scans the 196 block sums in LDS (redundant, cheap), then
// in-block exclusive scan of deg -> rowptr, cursor.
// ---------------------------------------------------------------------------
__global__ __launch_bounds__(256) void scan_final_kernel(
    const int* __restrict__ deg, const int* __restrict__ blocksum,
    int* __restrict__ rowptr, int* __restrict__ cursor)
{
    __shared__ int bs[256];
    __shared__ int s[256];
    int t = threadIdx.x;

    bs[t] = (t < SCAN_NBLK) ? blocksum[t] : 0;
    __syncthreads();
    for (int off = 1; off < 256; off <<= 1) {
        int v = (t >= off) ? bs[t - off] : 0;
        __syncthreads();
        bs[t] += v;
        __syncthreads();
    }
    int blockoff = (blockIdx.x == 0) ? 0 : bs[blockIdx.x - 1];

    int i = blockIdx.x * 256 + t;
    int v = (i < N_NODES) ? deg[i] : 0;
    s[t] = v;
    __syncthreads();
    for (int off = 1; off < 256; off <<= 1) {
        int u = (t >= off) ? s[t - off] : 0;
        __syncthreads();
        s[t] += u;
        __syncthreads();
    }
    int excl = s[t] - v + blockoff;
    if (i < N_NODES) {
        rowptr[i] = excl;
        cursor[i] = excl;
        if (i == N_NODES - 1) rowptr[N_NODES] = excl + v;
    }
}

// ---------------------------------------------------------------------------
// K3: scatter src ids into CSR slots (counting sort by dst)
// ---------------------------------------------------------------------------
__global__ __launch_bounds__(256) void csr_scatter_kernel(
    const int* __restrict__ src, const int* __restrict__ dst,
    int* __restrict__ cursor, int* __restrict__ csr_src)
{
    int e = blockIdx.x * blockDim.x + threadIdx.x;
    if (e >= N_EDGES) return;
    int pos = atomicAdd(&cursor[dst[e]], 1);
    csr_src[pos] = src[e];
}

// ---------------------------------------------------------------------------
// K4: per-dst-node fused dot + online softmax + weighted aggregate (fp32),
// r8's proven config (4-deep unroll, 8 nodes per 256-thr block, no barrier).
// Output written as BF16 (8B/lane) — the conversion the GEMM needed anyway;
// halves the neigh round-trip (25.6 -> 12.8 MB).
// ---------------------------------------------------------------------------
__global__ __launch_bounds__(256) void node_aggregate_kernel(
    const float* __restrict__ emb,
    const int* __restrict__ rowptr,
    const int* __restrict__ csr_src,
    ushort* __restrict__ neigh_bf)
{
    int node = blockIdx.x * 8 + (threadIdx.x >> 5);
    int lane = threadIdx.x & 31;
    if (node >= N_NODES) return;

    int beg = rowptr[node];
    int end = rowptr[node + 1];

    const float4 b = *((const float4*)(emb + (size_t)node * H_DIM) + lane);

    float m = -INFINITY;
    float denom = 0.f;
    float4 acc = {0.f, 0.f, 0.f, 0.f};

    int e = beg;
    for (; e + 4 <= end; e += 4) {
        float4 a[4];
        float  p[4];
        #pragma unroll
        for (int u = 0; u < 4; ++u) {
            int s = csr_src[e + u];
            a[u] = *((const float4*)(emb + (size_t)s * H_DIM) + lane);
        }
        #pragma unroll
        for (int u = 0; u < 4; ++u)
            p[u] = a[u].x * b.x + a[u].y * b.y + a[u].z * b.z + a[u].w * b.w;
        #pragma unroll
        for (int off = 16; off; off >>= 1) {
            #pragma unroll
            for (int u = 0; u < 4; ++u)
                p[u] += __shfl_xor(p[u], off);
        }
        float mn = fmaxf(fmaxf(fmaxf(p[0], p[1]), fmaxf(p[2], p[3])), m);
        float corr = __expf(m - mn);      // first iter: exp(-inf)=0
        float w[4];
        #pragma unroll
        for (int u = 0; u < 4; ++u) w[u] = __expf(p[u] - mn);
        denom = denom * corr + w[0] + w[1] + w[2] + w[3];
        acc.x = acc.x * corr + a[0].x*w[0] + a[1].x*w[1] + a[2].x*w[2] + a[3].x*w[3];
        acc.y = acc.y * corr + a[0].y*w[0] + a[1].y*w[1] + a[2].y*w[2] + a[3].y*w[3];
        acc.z = acc.z * corr + a[0].z*w[0] + a[1].z*w[1] + a[2].z*w[2] + a[3].z*w[3];
        acc.w = acc.w * corr + a[0].w*w[0] + a[1].w*w[1] + a[2].w*w[2] + a[3].w*w[3];
        m = mn;
    }
    for (; e < end; ++e) {
        int s = csr_src[e];
        float4 a = *((const float4*)(emb + (size_t)s * H_DIM) + lane);
        float p = a.x * b.x + a.y * b.y + a.z * b.z + a.w * b.w;
        #pragma unroll
        for (int off = 16; off; off >>= 1)
            p += __shfl_xor(p, off);
        float mn   = fmaxf(m, p);
        float corr = __expf(m - mn);
        float w    = __expf(p - mn);
        denom = denom * corr + w;
        acc.x = acc.x * corr + a.x * w;
        acc.y = acc.y * corr + a.y * w;
        acc.z = acc.z * corr + a.z * w;
        acc.w = acc.w * corr + a.w * w;
        m = mn;
    }

    float inv = (end > beg) ? (1.0f / denom) : 0.f;
    unsigned lo = (unsigned)f2bf(acc.x * inv) | ((unsigned)f2bf(acc.y * inv) << 16);
    unsigned hi = (unsigned)f2bf(acc.z * inv) | ((unsigned)f2bf(acc.w * inv) << 16);
    uint2 pk; pk.x = lo; pk.y = hi;
    *((uint2*)(neigh_bf + (size_t)node * H_DIM) + lane) = pk;
}

// ---------------------------------------------------------------------------
// K5: h = neigh_bf @ W via MFMA, NO data LDS: A-fragments read directly from
// global bf16 neigh (16B contiguous per lane), B-fragments from L2-hot wt.
// Only the 9 KB stats reduction lives in LDS -> high occupancy, no staging
// barrier (the fused version's barrier-imbalance tax is gone).
// Wave w -> rows (w>>1)*16, cols (w&1)*64; 4 col-tiles x 4 k-steps.
// C/D layout (m89): col=lane&15, row=(lane>>4)*4+reg.
// ---------------------------------------------------------------------------
__global__ __launch_bounds__(256) void gemm_stats_kernel(
    const ushort* __restrict__ neigh_bf,
    const ushort* __restrict__ wt,
    float* __restrict__ h,
    float* __restrict__ partial)
{
    __shared__ float red_s[128 * 9];   // 4.5 KB col-sum contributors
    __shared__ float red_q[128 * 9];   // 4.5 KB col-sq contributors

    int t  = threadIdx.x;
    int r0 = blockIdx.x * 32;

    int w      = t >> 6;
    int lane64 = t & 63;
    int rbase  = (w >> 1) * 16;
    int c0     = (w & 1) * 64;
    int l15    = lane64 & 15;
    int kgrp   = lane64 >> 4;           // 0..3
    int grow   = r0 + rbase + l15;      // global A-row this lane supplies
    int k0l    = kgrp * 8;

    floatx4 acc4[4] = {{0.f,0.f,0.f,0.f},{0.f,0.f,0.f,0.f},
                       {0.f,0.f,0.f,0.f},{0.f,0.f,0.f,0.f}};

    #pragma unroll
    for (int ks = 0; ks < 4; ++ks) {
        int k0 = ks * 32 + k0l;
        short8 af = {0,0,0,0,0,0,0,0};
        if (grow < N_NODES)
            af = *(const short8*)(neigh_bf + (size_t)grow * H_DIM + k0);
        #pragma unroll
        for (int ct = 0; ct < 4; ++ct) {
            int col = c0 + ct * 16 + l15;
            short8 bf = *(const short8*)(wt + (size_t)col * 128 + k0);
            acc4[ct] = __builtin_amdgcn_mfma_f32_16x16x32_bf16(af, bf, acc4[ct], 0, 0, 0);
        }
    }

    // epilogue: write h + per-thread column partials (padded rows have acc=0)
    int contrib = (w >> 1) * 4 + kgrp;   // 0..7 per column
    #pragma unroll
    for (int ct = 0; ct < 4; ++ct) {
        int col = c0 + ct * 16 + l15;
        float ps = 0.f, pq = 0.f;
        #pragma unroll
        for (int reg = 0; reg < 4; ++reg) {
            float v = acc4[ct][reg];
            int gr = r0 + rbase + kgrp * 4 + reg;
            if (gr < N_NODES) h[(size_t)gr * H_DIM + col] = v;
            ps += v;
            pq += v * v;
        }
        red_s[col * 9 + contrib] = ps;
        red_q[col * 9 + contrib] = pq;
    }
    __syncthreads();

    float s = 0.f;
    if (t < 128) {
        #pragma unroll
        for (int q = 0; q < 8; ++q) s += red_s[t * 9 + q];
    } else {
        #pragma unroll
        for (int q = 0; q < 8; ++q) s += red_q[(t - 128) * 9 + q];
    }
    partial[(size_t)blockIdx.x * 256 + t] = s;
}

// ---------------------------------------------------------------------------
// K6: stage-1 partial reduction: 64 blocks sum 1563 rows -> partial2[64][256]
// ---------------------------------------------------------------------------
__global__ __launch_bounds__(256) void reduce_partials_kernel(
    const float* __restrict__ partial, float* __restrict__ partial2)
{
    int t = threadIdx.x;
    int g = blockIdx.x;
    float s = 0.f;
    for (int b = g; b < GEMM_GRID; b += RED_NBLK)
        s += partial[(size_t)b * 256 + t];
    partial2[(size_t)g * 256 + t] = s;
}

// ---------------------------------------------------------------------------
// K7 (merged): each of 512 blocks redundantly folds the 64KB L2-hot partial2
// into scale/shift in LDS (~0.7us, unroll-8 overlapped), then grid-strides
// the normalize+tanh over h in place. Replaces bn_stats + bn_tanh.
// Layout: tot[c] = colsum, tot[128+c] = colsumsq.
// ---------------------------------------------------------------------------
__global__ __launch_bounds__(256) void bn_fold_tanh_kernel(
    const float* __restrict__ partial2,
    const float* __restrict__ gamma,
    const float* __restrict__ beta,
    float* __restrict__ h)
{
    __shared__ float tot[256];
    __shared__ float sc_s[128];
    __shared__ float sh_s[128];
    int t = threadIdx.x;

    float s = 0.f;
    #pragma unroll 8
    for (int b = 0; b < RED_NBLK; ++b)
        s += partial2[b * 256 + t];        // coalesced, L2-hot
    tot[t] = s;
    __syncthreads();
    if (t < 128) {
        float cs = tot[t];
        float cq = tot[t + 128];
        const float invN = 1.0f / (float)N_NODES;
        float mu  = cs * invN;
        float var = cq * invN - mu * mu;   // biased, matches jnp.var
        float sc  = gamma[t] * rsqrtf(var + BN_EPS);
        sc_s[t] = sc;
        sh_s[t] = beta[t] - mu * sc;
    }
    __syncthreads();

    const size_t total4 = (size_t)N_NODES * H_DIM / 4;
    for (size_t i = (size_t)blockIdx.x * 256 + t; i < total4;
         i += (size_t)gridDim.x * 256) {
        size_t idx4 = i * 4;
        int c = (int)(idx4 & (H_DIM - 1));
        float4 v = *(float4*)(h + idx4);
        v.x = tanhf(v.x * sc_s[c + 0] + sh_s[c + 0]);
        v.y = tanhf(v.y * sc_s[c + 1] + sh_s[c + 1]);
        v.z = tanhf(v.z * sc_s[c + 2] + sh_s[c + 2]);
        v.w = tanhf(v.w * sc_s[c + 3] + sh_s[c + 3]);
        *(float4*)(h + idx4) = v;
    }
}

// ---------------------------------------------------------------------------
extern "C" void kernel_launch(void* const* d_in, const int* in_sizes, int n_in,
                              void* d_out, int out_size, void* d_ws, size_t ws_size,
                              hipStream_t stream)
{
    const float* ent_emb = (const float*)d_in[0];
    const float* neigh_w = (const float*)d_in[1];
    const float* gamma   = (const float*)d_in[2];
    const float* beta    = (const float*)d_in[3];
    const int*   src     = (const int*)d_in[4];
    const int*   dst     = (const int*)d_in[5];
    float* out = (float*)d_out;

    int*    deg      = (int*)d_ws;                                   // 50000
    int*    rowptr   = deg + N_NODES;                                // 50001
    int*    cursor   = rowptr + N_NODES + 1;                         // 50000
    int*    csr_src  = cursor + N_NODES;                             // 500000
    int*    blocksum = csr_src + N_EDGES;                            // 196
    float*  partial  = (float*)(blocksum + SCAN_NBLK);               // 1563*256
    float*  partial2 = partial + (size_t)GEMM_GRID * 256;            // 64*256
    ushort* wt       = (ushort*)(partial2 + (size_t)RED_NBLK * 256); // 16384
    ushort* neigh_bf = wt + H_DIM * H_DIM;                           // 6.4M (12.8MB)

    hipMemsetAsync(deg, 0, N_NODES * sizeof(int), stream);

    // CSR build (counting sort by dst) + W->bf16^T fused into hist
    hist_cvt_kernel<<<(N_EDGES + 255) / 256, 256, 0, stream>>>(dst, deg, neigh_w, wt);
    scan_partial_kernel<<<SCAN_NBLK, 256, 0, stream>>>(deg, blocksum);
    scan_final_kernel<<<SCAN_NBLK, 256, 0, stream>>>(deg, blocksum, rowptr, cursor);
    csr_scatter_kernel<<<(N_EDGES + 255) / 256, 256, 0, stream>>>(src, dst, cursor, csr_src);

    // gather + online softmax + aggregate -> bf16 neigh (no barrier tax)
    node_aggregate_kernel<<<(N_NODES + 7) / 8, 256, 0, stream>>>(
        ent_emb, rowptr, csr_src, neigh_bf);

    // LDS-free MFMA GEMM: h = neigh_bf @ W + column partials
    gemm_stats_kernel<<<GEMM_GRID, 256, 0, stream>>>(neigh_bf, wt, out, partial);

    // hierarchical BN stats fold + normalize + tanh
    reduce_partials_kernel<<<RED_NBLK, 256, 0, stream>>>(partial, partial2);
    bn_fold_tanh_kernel<<<512, 256, 0, stream>>>(partial2, gamma, beta, out);
}